// Round 4
// baseline (1581.375 us; speedup 1.0000x reference)
//
#include <hip/hip_runtime.h>
#include <hip/hip_bf16.h>

// CrossAttentionSVD: fused LoRA-branch attention on MI355X (gfx950)
// B=16 N=1024 C=1280 H=8 D=160 R=64 -> per-head combined dim 224
// Pipeline: cvt X -> pack combined QKV weights (SCALE folded into Wq)
//   -> GEMM1 bf16 (16384x5376x1280) with split epilogue writing Q, K, VT(transposed V)
//   -> flash attn (head dim 224) -> GEMM2 bf16 (16384x1280x1792) + bias -> fp32 out
// Workspace: 239,468,544 B (~228.4 MiB). O2 aliases the dead XB+WQKV region.
// (Round 3 resubmission: rounds 0/2/3 were infra failures; statically re-audited.)

typedef __attribute__((ext_vector_type(8))) short bf16x8;
typedef __attribute__((ext_vector_type(4))) float f32x4;
typedef unsigned short ushort_t;

#define DEV static __device__ __forceinline__

DEV ushort_t f2bf(float f) {
  unsigned u = __builtin_bit_cast(unsigned, f);
  unsigned r = (u + 0x7fffu + ((u >> 16) & 1u)) >> 16;
  return (ushort_t)r;
}

DEV void gload_lds16(const void* g, void* l) {
  __builtin_amdgcn_global_load_lds(
      (const __attribute__((address_space(1))) unsigned int*)g,
      (__attribute__((address_space(3))) unsigned int*)l, 16, 0, 0);
}

// ---------------- pack kernels ----------------

__global__ void k_cvt_x(const float4* __restrict__ x, ushort4* __restrict__ out, int n4) {
  int i = blockIdx.x * 256 + threadIdx.x;
  if (i >= n4) return;
  float4 v = x[i];
  ushort4 o;
  o.x = f2bf(v.x); o.y = f2bf(v.y); o.z = f2bf(v.z); o.w = f2bf(v.w);
  out[i] = o;
}

// WqkvT: (5376 rows = [3][8][224]) x (1280 k), bf16, row-major.
// row j -> tensor t=j/1792, head h, within-head i; i<64 from W*_lr, else W*_full.
// Q rows (t==0) pre-scaled by SCALE = 160^-0.5.
__global__ void k_pack_wqkv(const float* __restrict__ wq_lr, const float* __restrict__ wk_lr,
                            const float* __restrict__ wv_lr, const float* __restrict__ wq_f,
                            const float* __restrict__ wk_f, const float* __restrict__ wv_f,
                            ushort_t* __restrict__ out) {
  int t = blockIdx.x * 256 + threadIdx.x;       // one thread per 4 k
  int j = t / 320;
  int k4 = (t - j * 320) * 4;
  int tt = j / 1792;
  int rem = j - tt * 1792;
  int h = rem / 224;
  int i = rem - h * 224;
  const float* src;
  int srow;
  if (i < 64) {
    src = (tt == 0) ? wq_lr : (tt == 1) ? wk_lr : wv_lr;
    srow = h * 64 + i;
  } else {
    src = (tt == 0) ? wq_f : (tt == 1) ? wk_f : wv_f;
    srow = h * 160 + (i - 64);
  }
  float sc = (tt == 0) ? 0.07905694150420949f : 1.0f;
  float4 v = *(const float4*)(src + (size_t)srow * 1280 + k4);
  ushort4 o;
  o.x = f2bf(v.x * sc); o.y = f2bf(v.y * sc); o.z = f2bf(v.z * sc); o.w = f2bf(v.w * sc);
  *(ushort4*)(out + (size_t)j * 1280 + k4) = o;
}

// WoT: (1280 rows = c) x (1792 k = [8][224]), bf16.
__global__ void k_pack_wo(const float* __restrict__ wo_lr, const float* __restrict__ wo_f,
                          ushort_t* __restrict__ out) {
  int t = blockIdx.x * 256 + threadIdx.x;       // one thread per 4 j
  int c = t / 448;
  int j = (t - c * 448) * 4;
  int h = j / 224;
  int i = j - h * 224;
  float4 v;
  if (i < 64) v = *(const float4*)(wo_lr + (size_t)c * 512 + h * 64 + i);
  else        v = *(const float4*)(wo_f + (size_t)c * 1280 + h * 160 + (i - 64));
  ushort4 o;
  o.x = f2bf(v.x); o.y = f2bf(v.y); o.z = f2bf(v.z); o.w = f2bf(v.w);
  *(ushort4*)(out + (size_t)c * 1792 + j) = o;
}

// ---------------- GEMM (m97 structure: 128x128 tile, BK=32, 4 waves) ----------------
// A: M x K bf16 row-major; Bt: N x K bf16 row-major; tile 128x128.
// EPI==0 (GEMM1): split epilogue. cols [0,1792)->Qr, [1792,3584)->Kr (both
//   [token][1792] bf16), [3584,5376)->VTr transposed ([bh][224][1024] bf16).
//   Class is block-uniform: boundaries 1792/3584 are multiples of 128.
// EPI==1 (GEMM2): fp32 C + bias[col].
template <int EPI>
__global__ __launch_bounds__(256, 2) void k_gemm(const ushort_t* __restrict__ A,
                                                 const ushort_t* __restrict__ Bt,
                                                 ushort_t* __restrict__ Qr,
                                                 ushort_t* __restrict__ Kr,
                                                 ushort_t* __restrict__ VTr,
                                                 float* __restrict__ Cf,
                                                 const float* __restrict__ bias,
                                                 int M, int N, int K) {
  __shared__ ushort_t lA[128 * 32];
  __shared__ ushort_t lB[128 * 32];
  const int tid = threadIdx.x;
  const int lane = tid & 63;
  const int lr = lane & 15, lg = lane >> 4;
  const int wid = tid >> 6;
  const int wr = (wid >> 1) * 64, wc = (wid & 1) * 64;
  const int m0 = blockIdx.x * 128, n0 = blockIdx.y * 128;

  f32x4 acc[4][4] = {};
  const int o0 = tid * 16;  // byte offset in 8KB tile

  for (int k0 = 0; k0 < K; k0 += 32) {
#pragma unroll
    for (int i = 0; i < 2; ++i) {
      int o = o0 + i * 4096;
      int row = o >> 6;      // 64B per row (32 bf16)
      int cb = o & 63;
      gload_lds16(A + (size_t)(m0 + row) * K + k0 + (cb >> 1), (void*)(lA + (o >> 1)));
      gload_lds16(Bt + (size_t)(n0 + row) * K + k0 + (cb >> 1), (void*)(lB + (o >> 1)));
    }
    __syncthreads();
    bf16x8 af[4], bfr[4];
#pragma unroll
    for (int mi = 0; mi < 4; ++mi)
      af[mi] = *(const bf16x8*)(lA + (wr + mi * 16 + lr) * 32 + lg * 8);
#pragma unroll
    for (int ni = 0; ni < 4; ++ni)
      bfr[ni] = *(const bf16x8*)(lB + (wc + ni * 16 + lr) * 32 + lg * 8);
#pragma unroll
    for (int mi = 0; mi < 4; ++mi)
#pragma unroll
      for (int ni = 0; ni < 4; ++ni)
        acc[mi][ni] = __builtin_amdgcn_mfma_f32_16x16x32_bf16(af[mi], bfr[ni], acc[mi][ni], 0, 0, 0);
    __syncthreads();
  }

  if (EPI == 1) {
#pragma unroll
    for (int mi = 0; mi < 4; ++mi)
#pragma unroll
      for (int ni = 0; ni < 4; ++ni) {
        int col = n0 + wc + ni * 16 + lr;
#pragma unroll
        for (int r = 0; r < 4; ++r) {
          int row = m0 + wr + mi * 16 + lg * 4 + r;
          Cf[(size_t)row * N + col] = acc[mi][ni][r] + bias[col];
        }
      }
  } else if (n0 < 3584) {
    ushort_t* base = (n0 < 1792) ? Qr : Kr;
    const int coff = (n0 < 1792) ? 0 : 1792;
#pragma unroll
    for (int mi = 0; mi < 4; ++mi)
#pragma unroll
      for (int ni = 0; ni < 4; ++ni) {
        int col = n0 + wc + ni * 16 + lr - coff;
#pragma unroll
        for (int r = 0; r < 4; ++r) {
          int row = m0 + wr + mi * 16 + lg * 4 + r;
          base[(size_t)row * 1792 + col] = f2bf(acc[mi][ni][r]);
        }
      }
  } else {
#pragma unroll
    for (int ni = 0; ni < 4; ++ni) {
      int j = n0 + wc + ni * 16 + lr - 3584;
      int h = j / 224;
      int d = j - h * 224;
#pragma unroll
      for (int mi = 0; mi < 4; ++mi)
#pragma unroll
        for (int r = 0; r < 4; ++r) {
          int row = m0 + wr + mi * 16 + lg * 4 + r;
          int b = row >> 10, n = row & 1023;
          VTr[((size_t)(b * 8 + h) * 224 + d) * 1024 + n] = f2bf(acc[mi][ni][r]);
        }
    }
  }
}

// ---------------- flash attention, head dim 224 ----------------
// grid 2048 = 128 bh * 16 q-tiles (XCD-chunked swizzle). 4 waves * 16 q-rows.
// Q pre-scaled by SCALE. K fragments read direct from L2; V from VT (bh,224,1024).
__global__ __launch_bounds__(256, 2) void k_attn(const ushort_t* __restrict__ qr,
                                                 const ushort_t* __restrict__ kr,
                                                 const ushort_t* __restrict__ vt,
                                                 ushort_t* __restrict__ o2) {
  __shared__ ushort_t plds[4][16 * 72];  // per-wave P buffer, stride 72 bf16
  const int tid = threadIdx.x, lane = tid & 63, wid = tid >> 6;
  const int lr = lane & 15, lg = lane >> 4;
  int bid = blockIdx.x;
  int w = ((bid & 7) << 8) | (bid >> 3);  // XCD-chunked: 256 consecutive work-units per XCD
  const int qt = w & 15, bh = w >> 4;
  const int b = bh >> 3, h = bh & 7;
  const int q0 = qt * 64 + wid * 16;

  const ushort_t* qrow = qr + (size_t)(b * 1024 + q0 + lr) * 1792 + h * 224;
  bf16x8 qf[7];
#pragma unroll
  for (int c = 0; c < 7; ++c) qf[c] = *(const bf16x8*)(qrow + c * 32 + lg * 8);

  f32x4 acc[14] = {};
  float m[4], l[4];
#pragma unroll
  for (int r = 0; r < 4; ++r) { m[r] = -3.0e38f; l[r] = 0.f; }

  const ushort_t* kbase = kr + (size_t)b * 1024 * 1792 + h * 224;
  const ushort_t* vbase = vt + (size_t)bh * 224 * 1024;
  ushort_t* pbuf = &plds[wid][0];
  const float L2E = 1.4426950408889634f;

  for (int kv0 = 0; kv0 < 1024; kv0 += 64) {
    f32x4 s[4] = {};
#pragma unroll
    for (int kb = 0; kb < 4; ++kb) {
      const ushort_t* kp = kbase + (size_t)(kv0 + kb * 16 + lr) * 1792;
#pragma unroll
      for (int c = 0; c < 7; ++c) {
        bf16x8 kf = *(const bf16x8*)(kp + c * 32 + lg * 8);
        s[kb] = __builtin_amdgcn_mfma_f32_16x16x32_bf16(qf[c], kf, s[kb], 0, 0, 0);
      }
    }
    float fr[4];
#pragma unroll
    for (int r = 0; r < 4; ++r) {
      float v = fmaxf(fmaxf(s[0][r], s[1][r]), fmaxf(s[2][r], s[3][r]));
      v = fmaxf(v, __shfl_xor(v, 1));
      v = fmaxf(v, __shfl_xor(v, 2));
      v = fmaxf(v, __shfl_xor(v, 4));
      v = fmaxf(v, __shfl_xor(v, 8));
      float mn = fmaxf(m[r], v);
      fr[r] = __builtin_exp2f((m[r] - mn) * L2E);
      float p0 = __builtin_exp2f((s[0][r] - mn) * L2E);
      float p1 = __builtin_exp2f((s[1][r] - mn) * L2E);
      float p2 = __builtin_exp2f((s[2][r] - mn) * L2E);
      float p3 = __builtin_exp2f((s[3][r] - mn) * L2E);
      float su = p0 + p1 + p2 + p3;
      su += __shfl_xor(su, 1);
      su += __shfl_xor(su, 2);
      su += __shfl_xor(su, 4);
      su += __shfl_xor(su, 8);
      l[r] = l[r] * fr[r] + su;
      m[r] = mn;
      int prow = (lg * 4 + r) * 72;
      pbuf[prow + 0 + lr] = f2bf(p0);
      pbuf[prow + 16 + lr] = f2bf(p1);
      pbuf[prow + 32 + lr] = f2bf(p2);
      pbuf[prow + 48 + lr] = f2bf(p3);
    }
#pragma unroll
    for (int db = 0; db < 14; ++db) {
      acc[db][0] *= fr[0]; acc[db][1] *= fr[1];
      acc[db][2] *= fr[2]; acc[db][3] *= fr[3];
    }
    __builtin_amdgcn_wave_barrier();  // order P writes before P reads (same wave, in-order LDS)
#pragma unroll
    for (int ch = 0; ch < 2; ++ch) {
      bf16x8 pa = *(const bf16x8*)(pbuf + lr * 72 + ch * 32 + lg * 8);
      const ushort_t* vp = vbase + kv0 + ch * 32 + lg * 8;
#pragma unroll
      for (int db = 0; db < 14; ++db) {
        bf16x8 vf = *(const bf16x8*)(vp + (size_t)(db * 16 + lr) * 1024);
        acc[db] = __builtin_amdgcn_mfma_f32_16x16x32_bf16(pa, vf, acc[db], 0, 0, 0);
      }
    }
  }
  float inv[4];
#pragma unroll
  for (int r = 0; r < 4; ++r) inv[r] = 1.0f / l[r];
  ushort_t* orow = o2 + (size_t)(b * 1024 + q0) * 1792 + h * 224;
#pragma unroll
  for (int db = 0; db < 14; ++db)
#pragma unroll
    for (int r = 0; r < 4; ++r)
      orow[(size_t)(lg * 4 + r) * 1792 + db * 16 + lr] = f2bf(acc[db][r] * inv[r]);
}

// ---------------- launch ----------------

extern "C" void kernel_launch(void* const* d_in, const int* in_sizes, int n_in,
                              void* d_out, int out_size, void* d_ws, size_t ws_size,
                              hipStream_t stream) {
  const float* hs    = (const float*)d_in[0];
  const float* wq_lr = (const float*)d_in[1];
  const float* wk_lr = (const float*)d_in[2];
  const float* wv_lr = (const float*)d_in[3];
  const float* wo_lr = (const float*)d_in[4];
  const float* wq_f  = (const float*)d_in[5];
  const float* wk_f  = (const float*)d_in[6];
  const float* wv_f  = (const float*)d_in[7];
  const float* wo_f  = (const float*)d_in[8];
  const float* bias  = (const float*)d_in[9];

  const size_t SZ_WOT = (size_t)1280 * 1792 * 2;    //  4,587,520
  const size_t SZ_BIG = (size_t)16384 * 1792 * 2;   // 58,720,256
  char* p = (char*)d_ws;
  ushort_t* WOT = (ushort_t*)p; p += SZ_WOT;
  // region0: XB (40 MB) + WQKV (13.1 MB) live through GEMM1, then O2 aliases it
  char* region0 = p;
  ushort_t* XB   = (ushort_t*)region0;
  ushort_t* WQKV = (ushort_t*)(region0 + (size_t)16384 * 1280 * 2);
  ushort_t* O2   = (ushort_t*)region0;
  p += SZ_BIG;
  ushort_t* Qr  = (ushort_t*)p; p += SZ_BIG;
  ushort_t* Kr  = (ushort_t*)p; p += SZ_BIG;
  ushort_t* VTr = (ushort_t*)p; p += SZ_BIG;
  // total: 4,587,520 + 4*58,720,256 = 239,468,544 B (~228.4 MiB)

  k_cvt_x<<<dim3(20480), dim3(256), 0, stream>>>((const float4*)hs, (ushort4*)XB, 5242880);
  k_pack_wqkv<<<dim3(6720), dim3(256), 0, stream>>>(wq_lr, wk_lr, wv_lr, wq_f, wk_f, wv_f, WQKV);
  k_pack_wo<<<dim3(2240), dim3(256), 0, stream>>>(wo_lr, wo_f, WOT);
  k_gemm<0><<<dim3(128, 42), dim3(256), 0, stream>>>(XB, WQKV, Qr, Kr, VTr, nullptr, nullptr, 16384, 5376, 1280);
  k_attn<<<dim3(2048), dim3(256), 0, stream>>>(Qr, Kr, VTr, O2);
  k_gemm<1><<<dim3(128, 10), dim3(256), 0, stream>>>(O2, WOT, nullptr, nullptr, nullptr, (float*)d_out, bias, 16384, 1280, 1792);
}

// Round 5
// 864.611 us; speedup vs baseline: 1.8290x; 1.8290x over previous
//
#include <hip/hip_runtime.h>
#include <hip/hip_bf16.h>

// CrossAttentionSVD: fused LoRA-branch attention on MI355X (gfx950)
// B=16 N=1024 C=1280 H=8 D=160 R=64 -> per-head combined dim 224
// Pipeline: cvt X -> pack combined QKV weights (SCALE folded into Wq)
//   -> GEMM1 bf16 (16384x5376x1280) with split epilogue writing Q, K, VT(transposed V)
//   -> flash attn (head dim 224, LDS-staged double-buffered K/V) -> GEMM2 + bias -> fp32
// Round 4 -> 5 change: k_attn restructured from direct-global K/V reads (latency-bound,
// MfmaUtil 4.7%) to 2-phase pipelined LDS staging via global_load_lds (KVBLK=32,
// padded strides = uniform bank spread, setprio around MFMA).

typedef __attribute__((ext_vector_type(8))) short bf16x8;
typedef __attribute__((ext_vector_type(4))) float f32x4;
typedef unsigned short ushort_t;

#define DEV static __device__ __forceinline__

DEV ushort_t f2bf(float f) {
  unsigned u = __builtin_bit_cast(unsigned, f);
  unsigned r = (u + 0x7fffu + ((u >> 16) & 1u)) >> 16;
  return (ushort_t)r;
}

DEV void gload_lds16(const void* g, void* l) {
  __builtin_amdgcn_global_load_lds(
      (const __attribute__((address_space(1))) unsigned int*)g,
      (__attribute__((address_space(3))) unsigned int*)l, 16, 0, 0);
}

// ---------------- pack kernels ----------------

__global__ void k_cvt_x(const float4* __restrict__ x, ushort4* __restrict__ out, int n4) {
  int i = blockIdx.x * 256 + threadIdx.x;
  if (i >= n4) return;
  float4 v = x[i];
  ushort4 o;
  o.x = f2bf(v.x); o.y = f2bf(v.y); o.z = f2bf(v.z); o.w = f2bf(v.w);
  out[i] = o;
}

// WqkvT: (5376 rows = [3][8][224]) x (1280 k), bf16, row-major. Q rows pre-scaled.
__global__ void k_pack_wqkv(const float* __restrict__ wq_lr, const float* __restrict__ wk_lr,
                            const float* __restrict__ wv_lr, const float* __restrict__ wq_f,
                            const float* __restrict__ wk_f, const float* __restrict__ wv_f,
                            ushort_t* __restrict__ out) {
  int t = blockIdx.x * 256 + threadIdx.x;       // one thread per 4 k
  int j = t / 320;
  int k4 = (t - j * 320) * 4;
  int tt = j / 1792;
  int rem = j - tt * 1792;
  int h = rem / 224;
  int i = rem - h * 224;
  const float* src;
  int srow;
  if (i < 64) {
    src = (tt == 0) ? wq_lr : (tt == 1) ? wk_lr : wv_lr;
    srow = h * 64 + i;
  } else {
    src = (tt == 0) ? wq_f : (tt == 1) ? wk_f : wv_f;
    srow = h * 160 + (i - 64);
  }
  float sc = (tt == 0) ? 0.07905694150420949f : 1.0f;
  float4 v = *(const float4*)(src + (size_t)srow * 1280 + k4);
  ushort4 o;
  o.x = f2bf(v.x * sc); o.y = f2bf(v.y * sc); o.z = f2bf(v.z * sc); o.w = f2bf(v.w * sc);
  *(ushort4*)(out + (size_t)j * 1280 + k4) = o;
}

// WoT: (1280 rows = c) x (1792 k = [8][224]), bf16.
__global__ void k_pack_wo(const float* __restrict__ wo_lr, const float* __restrict__ wo_f,
                          ushort_t* __restrict__ out) {
  int t = blockIdx.x * 256 + threadIdx.x;       // one thread per 4 j
  int c = t / 448;
  int j = (t - c * 448) * 4;
  int h = j / 224;
  int i = j - h * 224;
  float4 v;
  if (i < 64) v = *(const float4*)(wo_lr + (size_t)c * 512 + h * 64 + i);
  else        v = *(const float4*)(wo_f + (size_t)c * 1280 + h * 160 + (i - 64));
  ushort4 o;
  o.x = f2bf(v.x); o.y = f2bf(v.y); o.z = f2bf(v.z); o.w = f2bf(v.w);
  *(ushort4*)(out + (size_t)c * 1792 + j) = o;
}

// ---------------- GEMM (m97 structure: 128x128 tile, BK=32, 4 waves) ----------------
template <int EPI>
__global__ __launch_bounds__(256, 2) void k_gemm(const ushort_t* __restrict__ A,
                                                 const ushort_t* __restrict__ Bt,
                                                 ushort_t* __restrict__ Qr,
                                                 ushort_t* __restrict__ Kr,
                                                 ushort_t* __restrict__ VTr,
                                                 float* __restrict__ Cf,
                                                 const float* __restrict__ bias,
                                                 int M, int N, int K) {
  __shared__ ushort_t lA[128 * 32];
  __shared__ ushort_t lB[128 * 32];
  const int tid = threadIdx.x;
  const int lane = tid & 63;
  const int lr = lane & 15, lg = lane >> 4;
  const int wid = tid >> 6;
  const int wr = (wid >> 1) * 64, wc = (wid & 1) * 64;
  const int m0 = blockIdx.x * 128, n0 = blockIdx.y * 128;

  f32x4 acc[4][4] = {};
  const int o0 = tid * 16;  // byte offset in 8KB tile

  for (int k0 = 0; k0 < K; k0 += 32) {
#pragma unroll
    for (int i = 0; i < 2; ++i) {
      int o = o0 + i * 4096;
      int row = o >> 6;      // 64B per row (32 bf16)
      int cb = o & 63;
      gload_lds16(A + (size_t)(m0 + row) * K + k0 + (cb >> 1), (void*)(lA + (o >> 1)));
      gload_lds16(Bt + (size_t)(n0 + row) * K + k0 + (cb >> 1), (void*)(lB + (o >> 1)));
    }
    __syncthreads();
    bf16x8 af[4], bfr[4];
#pragma unroll
    for (int mi = 0; mi < 4; ++mi)
      af[mi] = *(const bf16x8*)(lA + (wr + mi * 16 + lr) * 32 + lg * 8);
#pragma unroll
    for (int ni = 0; ni < 4; ++ni)
      bfr[ni] = *(const bf16x8*)(lB + (wc + ni * 16 + lr) * 32 + lg * 8);
#pragma unroll
    for (int mi = 0; mi < 4; ++mi)
#pragma unroll
      for (int ni = 0; ni < 4; ++ni)
        acc[mi][ni] = __builtin_amdgcn_mfma_f32_16x16x32_bf16(af[mi], bfr[ni], acc[mi][ni], 0, 0, 0);
    __syncthreads();
  }

  if (EPI == 1) {
#pragma unroll
    for (int mi = 0; mi < 4; ++mi)
#pragma unroll
      for (int ni = 0; ni < 4; ++ni) {
        int col = n0 + wc + ni * 16 + lr;
#pragma unroll
        for (int r = 0; r < 4; ++r) {
          int row = m0 + wr + mi * 16 + lg * 4 + r;
          Cf[(size_t)row * N + col] = acc[mi][ni][r] + bias[col];
        }
      }
  } else if (n0 < 3584) {
    ushort_t* base = (n0 < 1792) ? Qr : Kr;
    const int coff = (n0 < 1792) ? 0 : 1792;
#pragma unroll
    for (int mi = 0; mi < 4; ++mi)
#pragma unroll
      for (int ni = 0; ni < 4; ++ni) {
        int col = n0 + wc + ni * 16 + lr - coff;
#pragma unroll
        for (int r = 0; r < 4; ++r) {
          int row = m0 + wr + mi * 16 + lg * 4 + r;
          base[(size_t)row * 1792 + col] = f2bf(acc[mi][ni][r]);
        }
      }
  } else {
#pragma unroll
    for (int ni = 0; ni < 4; ++ni) {
      int j = n0 + wc + ni * 16 + lr - 3584;
      int h = j / 224;
      int d = j - h * 224;
#pragma unroll
      for (int mi = 0; mi < 4; ++mi)
#pragma unroll
        for (int r = 0; r < 4; ++r) {
          int row = m0 + wr + mi * 16 + lg * 4 + r;
          int b = row >> 10, n = row & 1023;
          VTr[((size_t)(b * 8 + h) * 224 + d) * 1024 + n] = f2bf(acc[mi][ni][r]);
        }
    }
  }
}

// ---------------- flash attention, head dim 224, LDS-staged K/V ----------------
// grid 2048 = 128 bh * 16 q-tiles (XCD-chunked). 4 waves * 16 q-rows. KVBLK=32.
// Dynamic LDS 78,848 B: K dbuf 2x16384 (rows 232sh: 28 data chunks + pad),
// V dbuf 2x20480 (rows 40sh: 4 data chunks + pad), P 4x16x40sh.
// Strides 232/40 shorts ≡ 4 mod 32 words -> uniform bank spread for b128 reads.
// 2-phase: stage tile t+1 (global_load_lds, per-lane src addr, pad slots clamped),
// compute tile t, one __syncthreads (vmcnt drain) per tile.
__global__ __launch_bounds__(256, 2) void k_attn(const ushort_t* __restrict__ qr,
                                                 const ushort_t* __restrict__ kr,
                                                 const ushort_t* __restrict__ vt,
                                                 ushort_t* __restrict__ o2) {
  extern __shared__ char smem[];
  const int tid = threadIdx.x, lane = tid & 63, wid = tid >> 6;
  const int lr = lane & 15, lg = lane >> 4;
  int bid = blockIdx.x;
  int w = ((bid & 7) << 8) | (bid >> 3);  // XCD-chunked: 256 consecutive work-units per XCD
  const int qt = w & 15, bh = w >> 4;
  const int b = bh >> 3, h = bh & 7;
  const int q0 = qt * 64 + wid * 16;

  // Q fragments (rows q0+lr, cols c*32+lg*8), pre-scaled by SCALE at pack time
  const ushort_t* qrow = qr + (size_t)(b * 1024 + q0 + lr) * 1792 + h * 224;
  bf16x8 qf[7];
#pragma unroll
  for (int c = 0; c < 7; ++c) qf[c] = *(const bf16x8*)(qrow + c * 32 + lg * 8);

  // staging sources: per-thread fixed (row, chunk) per slot; pad slots clamped safe.
  // K tile: 32 rows x 232sh, data chunks 0..27 (16B each), 29 chunks/row, 928 slots -> 4x256
  const ushort_t* ksrc[4];
#pragma unroll
  for (int i = 0; i < 4; ++i) {
    int slot = i * 256 + tid; if (slot > 927) slot = 927;
    int row = slot / 29, ch = slot - row * 29; if (ch > 27) ch = 0;
    ksrc[i] = kr + (size_t)(b * 1024 + row) * 1792 + h * 224 + ch * 8;
  }
  // V tile: 224 rows x 40sh, data chunks 0..3, 5 chunks/row, 1120 slots -> 5x256
  const ushort_t* vsrc[5];
#pragma unroll
  for (int j = 0; j < 5; ++j) {
    int slot = j * 256 + tid; if (slot > 1119) slot = 1119;
    int d = slot / 5, c = slot - d * 5; if (c > 3) c = 0;
    vsrc[j] = vt + (size_t)(bh * 224 + d) * 1024 + c * 8;
  }

  f32x4 acc[14] = {};
  float m[4], l[4];
#pragma unroll
  for (int r = 0; r < 4; ++r) { m[r] = -3.0e38f; l[r] = 0.f; }

  ushort_t* pbuf = (ushort_t*)(smem + 73728) + wid * 16 * 40;
  const float L2E = 1.4426950408889634f;

  // prologue: stage tile 0 into buffer 0
  {
    ushort_t* kd = (ushort_t*)smem;
    ushort_t* vd = (ushort_t*)(smem + 32768);
#pragma unroll
    for (int i = 0; i < 4; ++i) gload_lds16(ksrc[i], kd + i * 2048 + tid * 8);
#pragma unroll
    for (int j = 0; j < 5; ++j) gload_lds16(vsrc[j], vd + j * 2048 + tid * 8);
  }
  __syncthreads();

  for (int t = 0; t < 32; ++t) {
    const int cur = t & 1;
    if (t < 31) {  // stage tile t+1 into the other buffer (read-free this iter)
      ushort_t* kd = (ushort_t*)(smem + (cur ^ 1) * 16384);
      ushort_t* vd = (ushort_t*)(smem + 32768 + (cur ^ 1) * 20480);
      const size_t kadv = (size_t)(t + 1) * 32 * 1792;
      const int vadv = (t + 1) * 32;
#pragma unroll
      for (int i = 0; i < 4; ++i) gload_lds16(ksrc[i] + kadv, kd + i * 2048 + tid * 8);
#pragma unroll
      for (int j = 0; j < 5; ++j) gload_lds16(vsrc[j] + vadv, vd + j * 2048 + tid * 8);
    }
    const ushort_t* kbuf = (const ushort_t*)(smem + cur * 16384);
    const ushort_t* vbuf = (const ushort_t*)(smem + 32768 + cur * 20480);

    // QK^T: s[kb][r] = score[q=lg*4+r][kv = kb*16+lr]
    f32x4 s[2] = {};
    __builtin_amdgcn_s_setprio(1);
#pragma unroll
    for (int kb = 0; kb < 2; ++kb) {
      const ushort_t* kp = kbuf + (kb * 16 + lr) * 232;
#pragma unroll
      for (int c = 0; c < 7; ++c) {
        bf16x8 kf = *(const bf16x8*)(kp + c * 32 + lg * 8);
        s[kb] = __builtin_amdgcn_mfma_f32_16x16x32_bf16(qf[c], kf, s[kb], 0, 0, 0);
      }
    }
    __builtin_amdgcn_s_setprio(0);

    // online softmax over 32 kv (reduce across lr: 16-lane groups)
    float fr[4];
#pragma unroll
    for (int r = 0; r < 4; ++r) {
      float v = fmaxf(s[0][r], s[1][r]);
      v = fmaxf(v, __shfl_xor(v, 1));
      v = fmaxf(v, __shfl_xor(v, 2));
      v = fmaxf(v, __shfl_xor(v, 4));
      v = fmaxf(v, __shfl_xor(v, 8));
      float mn = fmaxf(m[r], v);
      fr[r] = __builtin_exp2f((m[r] - mn) * L2E);
      float p0 = __builtin_exp2f((s[0][r] - mn) * L2E);
      float p1 = __builtin_exp2f((s[1][r] - mn) * L2E);
      float su = p0 + p1;
      su += __shfl_xor(su, 1);
      su += __shfl_xor(su, 2);
      su += __shfl_xor(su, 4);
      su += __shfl_xor(su, 8);
      l[r] = l[r] * fr[r] + su;
      m[r] = mn;
      int prow = (lg * 4 + r) * 40;
      pbuf[prow + lr] = f2bf(p0);
      pbuf[prow + 16 + lr] = f2bf(p1);
    }
#pragma unroll
    for (int db = 0; db < 14; ++db) {
      acc[db][0] *= fr[0]; acc[db][1] *= fr[1];
      acc[db][2] *= fr[2]; acc[db][3] *= fr[3];
    }
    __builtin_amdgcn_wave_barrier();  // order P writes before P read (wave-local LDS)

    // PV: A = P(16q x 32kv), B^T = V[d][kv]; 14 d-blocks
    bf16x8 pa = *(const bf16x8*)(pbuf + lr * 40 + lg * 8);
    __builtin_amdgcn_s_setprio(1);
#pragma unroll
    for (int db = 0; db < 14; ++db) {
      bf16x8 vf = *(const bf16x8*)(vbuf + (db * 16 + lr) * 40 + lg * 8);
      acc[db] = __builtin_amdgcn_mfma_f32_16x16x32_bf16(pa, vf, acc[db], 0, 0, 0);
    }
    __builtin_amdgcn_s_setprio(0);
    __syncthreads();  // drains vmcnt(0): tile t+1 staged & visible; buffers swap
  }

  float inv[4];
#pragma unroll
  for (int r = 0; r < 4; ++r) inv[r] = 1.0f / l[r];
  ushort_t* orow = o2 + (size_t)(b * 1024 + q0) * 1792 + h * 224;
#pragma unroll
  for (int db = 0; db < 14; ++db)
#pragma unroll
    for (int r = 0; r < 4; ++r)
      orow[(size_t)(lg * 4 + r) * 1792 + db * 16 + lr] = f2bf(acc[db][r] * inv[r]);
}

// ---------------- launch ----------------

extern "C" void kernel_launch(void* const* d_in, const int* in_sizes, int n_in,
                              void* d_out, int out_size, void* d_ws, size_t ws_size,
                              hipStream_t stream) {
  const float* hs    = (const float*)d_in[0];
  const float* wq_lr = (const float*)d_in[1];
  const float* wk_lr = (const float*)d_in[2];
  const float* wv_lr = (const float*)d_in[3];
  const float* wo_lr = (const float*)d_in[4];
  const float* wq_f  = (const float*)d_in[5];
  const float* wk_f  = (const float*)d_in[6];
  const float* wv_f  = (const float*)d_in[7];
  const float* wo_f  = (const float*)d_in[8];
  const float* bias  = (const float*)d_in[9];

  const size_t SZ_WOT = (size_t)1280 * 1792 * 2;    //  4,587,520
  const size_t SZ_BIG = (size_t)16384 * 1792 * 2;   // 58,720,256
  char* p = (char*)d_ws;
  ushort_t* WOT = (ushort_t*)p; p += SZ_WOT;
  // region0: XB (40 MB) + WQKV (13.1 MB) live through GEMM1, then O2 aliases it
  char* region0 = p;
  ushort_t* XB   = (ushort_t*)region0;
  ushort_t* WQKV = (ushort_t*)(region0 + (size_t)16384 * 1280 * 2);
  ushort_t* O2   = (ushort_t*)region0;
  p += SZ_BIG;
  ushort_t* Qr  = (ushort_t*)p; p += SZ_BIG;
  ushort_t* Kr  = (ushort_t*)p; p += SZ_BIG;
  ushort_t* VTr = (ushort_t*)p; p += SZ_BIG;
  // total: 4,587,520 + 4*58,720,256 = 239,468,544 B (~228.4 MiB)

  hipFuncSetAttribute((const void*)k_attn, hipFuncAttributeMaxDynamicSharedMemorySize, 78848);

  k_cvt_x<<<dim3(20480), dim3(256), 0, stream>>>((const float4*)hs, (ushort4*)XB, 5242880);
  k_pack_wqkv<<<dim3(6720), dim3(256), 0, stream>>>(wq_lr, wk_lr, wv_lr, wq_f, wk_f, wv_f, WQKV);
  k_pack_wo<<<dim3(2240), dim3(256), 0, stream>>>(wo_lr, wo_f, WOT);
  k_gemm<0><<<dim3(128, 42), dim3(256), 0, stream>>>(XB, WQKV, Qr, Kr, VTr, nullptr, nullptr, 16384, 5376, 1280);
  k_attn<<<dim3(2048), dim3(256), 78848, stream>>>(Qr, Kr, VTr, O2);
  k_gemm<1><<<dim3(128, 10), dim3(256), 0, stream>>>(O2, WOT, nullptr, nullptr, nullptr, (float*)d_out, bias, 16384, 1280, 1792);
}